// Round 2
// baseline (513.268 us; speedup 1.0000x reference)
//
#include <hip/hip_runtime.h>

typedef unsigned short u16;
typedef unsigned int   u32;
typedef __attribute__((ext_vector_type(8))) short short8;  // 8 bf16 (4 VGPRs)
typedef __attribute__((ext_vector_type(4))) float f32x4;

#define MFMA16(a, b, c) __builtin_amdgcn_mfma_f32_16x16x32_bf16((a), (b), (c), 0, 0, 0)

static constexpr int B_ = 8;
static constexpr int HW = 3136;   // 56*56
static constexpr int KW = 784;    // 28*28
static constexpr int NELEM = B_ * 256 * HW;  // 6422528

// ---- workspace layout (bytes). Needs ~39.1 MB of d_ws. ----
static constexpr size_t OFF_CNT = 4096;   // int: dtype-detect counter (>=64 -> f32 inputs)
static constexpr size_t OFF_W   = 8192;   // bf16 weight arena
// arena offsets in u16 units
static constexpr int AOFF_WQ = 0, AOFF_WK = 65536, AOFF_WV = 131072, AOFF_WO = 196608;
static constexpr int AOFF_WKDW = 262144, AOFF_WVDW = 264448;
static constexpr int AOFF_BKDW = 266752, AOFF_BVDW = 267008, AOFF_BQ = 267264;
static constexpr int AOFF_BK = 267520, AOFF_BV = 267776, AOFF_BO = 268032;
static constexpr size_t OFF_XT  = 557056;
static constexpr size_t SZ_XT   = (size_t)B_ * HW * 256 * 2;  // 12845056
static constexpr size_t SZ_KJ   = (size_t)B_ * KW * 256 * 2;  // 3211264
static constexpr size_t OFF_KIT = OFF_XT + SZ_XT;
static constexpr size_t OFF_VIT = OFF_KIT + SZ_KJ;
static constexpr size_t OFF_KI  = OFF_VIT + SZ_KJ;  // conv-k out, later reused for k-proj out
static constexpr size_t OFF_VI  = OFF_KI + SZ_KJ;   // conv-v out, later reused for vT
static constexpr size_t OFF_Q   = OFF_VI + SZ_KJ;
static constexpr size_t OFF_O   = OFF_XT;           // overlays xt (dead after proj_q)

__device__ __forceinline__ float bf2f(u16 u) { return __uint_as_float(((u32)u) << 16); }
__device__ __forceinline__ u16 f2bf(float f) {
  u32 u = __float_as_uint(f);
  u32 r = u + 0x7FFFu + ((u >> 16) & 1u);
  return (u16)(r >> 16);
}
__device__ __forceinline__ float bflo(u32 u) { return __uint_as_float(u << 16); }
__device__ __forceinline__ float bfhi(u32 u) { return __uint_as_float(u & 0xFFFF0000u); }
__device__ __forceinline__ u32 packbf(float a, float b) {
  u32 ua = __float_as_uint(a); ua = (ua + 0x7FFFu + ((ua >> 16) & 1u)) >> 16;
  u32 ub = __float_as_uint(b); ub = (ub + 0x7FFFu + ((ub >> 16) & 1u)) >> 16;
  return ua | (ub << 16);
}

// ---- dtype detect: low 16 bits of first 4096 words of x, decoded as bf16.
// bf16 input: low half IS an element of N(0,1) -> never >1e4. f32 input: low half is
// random mantissa bits -> ~44% decode to |v|>1e4.
__global__ __launch_bounds__(256) void detect_k(const u32* __restrict__ x, int* __restrict__ cnt) {
  int c = 0;
  for (int i = threadIdx.x; i < 4096; i += 256) {
    float v = __uint_as_float(x[i] << 16);
    if (fabsf(v) > 1e4f) c++;
  }
#pragma unroll
  for (int off = 32; off > 0; off >>= 1) c += __shfl_down(c, off);
  if ((threadIdx.x & 63) == 0) atomicAdd(cnt, c);
}

// ---- canonicalize 12 weight/bias tensors into bf16 arena ----
struct CvtArgs { const void* src[12]; int dstoff[12]; int n[12]; };
__global__ __launch_bounds__(256) void cvtw_k(CvtArgs a, u16* __restrict__ arena,
                                              const int* __restrict__ cnt) {
  int t = blockIdx.y;
  int n = a.n[t];
  u16* d = arena + a.dstoff[t];
  int f32m = (*cnt >= 64);
  if (f32m) {
    const float* s = (const float*)a.src[t];
    for (int i = blockIdx.x * 256 + threadIdx.x; i < n; i += gridDim.x * 256) d[i] = f2bf(s[i]);
  } else {
    const u16* s = (const u16*)a.src[t];
    for (int i = blockIdx.x * 256 + threadIdx.x; i < n; i += gridDim.x * 256) d[i] = s[i];
  }
}

// ---- global sum / sumsq of x (single-scalar LayerNorm), dual dtype ----
__global__ __launch_bounds__(256) void reduce_k(const void* __restrict__ x, double* __restrict__ acc,
                                                const int* __restrict__ cnt) {
  int f32m = (*cnt >= 64);
  float s = 0.f, ss = 0.f;
  if (f32m) {
    const float4* xv = (const float4*)x;
    const int n4 = NELEM / 4;
    for (int i = blockIdx.x * 256 + threadIdx.x; i < n4; i += gridDim.x * 256) {
      float4 u = xv[i];
      s += u.x + u.y + u.z + u.w;
      ss += u.x * u.x + u.y * u.y + u.z * u.z + u.w * u.w;
    }
  } else {
    const uint4* xv = (const uint4*)x;
    const int n8 = NELEM / 8;
    for (int i = blockIdx.x * 256 + threadIdx.x; i < n8; i += gridDim.x * 256) {
      uint4 u = xv[i];
      u32 w[4] = {u.x, u.y, u.z, u.w};
#pragma unroll
      for (int q = 0; q < 4; q++) {
        float f0 = __uint_as_float(w[q] << 16);
        float f1 = __uint_as_float(w[q] & 0xFFFF0000u);
        s += f0 + f1;
        ss += f0 * f0 + f1 * f1;
      }
    }
  }
#pragma unroll
  for (int off = 32; off > 0; off >>= 1) {
    s += __shfl_down(s, off);
    ss += __shfl_down(ss, off);
  }
  __shared__ float as_[4], ass_[4];
  int wv = threadIdx.x >> 6;
  if ((threadIdx.x & 63) == 0) { as_[wv] = s; ass_[wv] = ss; }
  __syncthreads();
  if (threadIdx.x == 0) {
    atomicAdd(acc + 0, (double)(as_[0] + as_[1] + as_[2] + as_[3]));
    atomicAdd(acc + 1, (double)(ass_[0] + ass_[1] + ass_[2] + ass_[3]));
  }
}

// ---- mu/rstd + folded Q-projection constants (weights already bf16 in arena) ----
__global__ __launch_bounds__(256) void prep_k(const u16* __restrict__ wq, const u16* __restrict__ bq,
                                              float* __restrict__ wsf) {
  const double* acc = (const double*)wsf;
  __shared__ float sh[2];
  if (threadIdx.x == 0) {
    double N = (double)NELEM;
    double mu = acc[0] / N;
    double var = acc[1] / N - mu * mu;
    float rstd = (float)(1.0 / sqrt(var + 1e-5));
    sh[0] = (float)mu; sh[1] = rstd;
    wsf[4] = (float)mu; wsf[5] = rstd;
    wsf[6] = rstd * 0.17677669529663687f;  // rstd / sqrt(32)
  }
  __syncthreads();
  int o = threadIdx.x;
  float wsum = 0.f;
  for (int c = 0; c < 256; c++) wsum += bf2f(wq[o * 256 + c]);
  wsf[16 + o] = (bf2f(bq[o]) - sh[1] * sh[0] * wsum) * 0.17677669529663687f;
}

// ---- x [b][256][3136] -> xt [b][3136][256], dual dtype, bf16 out ----
__global__ __launch_bounds__(256) void transpose_x_k(const void* __restrict__ src, u16* __restrict__ dst,
                                                     const int* __restrict__ cnt) {
  int f32m = (*cnt >= 64);
  __shared__ u16 t[32][33];
  int b = blockIdx.z;
  int r0 = blockIdx.y * 32, c0 = blockIdx.x * 32;
  int tid = threadIdx.x, col = tid & 31;
  size_t base = (size_t)b * 256 * HW;
  if (f32m) {
    const float* s = (const float*)src + base;
#pragma unroll
    for (int i = 0; i < 4; i++) {
      int row = (tid >> 5) + i * 8;
      t[row][col] = f2bf(s[(size_t)(r0 + row) * HW + c0 + col]);
    }
  } else {
    const u16* s = (const u16*)src + base;
#pragma unroll
    for (int i = 0; i < 4; i++) {
      int row = (tid >> 5) + i * 8;
      t[row][col] = s[(size_t)(r0 + row) * HW + c0 + col];
    }
  }
  __syncthreads();
  u16* d = dst + base;
#pragma unroll
  for (int i = 0; i < 4; i++) {
    int row = (tid >> 5) + i * 8;  // indexes HW-dim in dst
    d[(size_t)(c0 + row) * 256 + r0 + col] = t[col][row];
  }
}

// ---- generic bf16 per-batch [R][Cc] -> [Cc][R] transpose (for conv outputs) ----
__global__ __launch_bounds__(256) void transpose_k(const u16* __restrict__ src, u16* __restrict__ dst,
                                                   int R, int Cc) {
  __shared__ u16 t[32][33];
  int b = blockIdx.z;
  int r0 = blockIdx.y * 32, c0 = blockIdx.x * 32;
  const u16* s = src + (size_t)b * R * Cc;
  u16* d = dst + (size_t)b * R * Cc;
  int tid = threadIdx.x, col = tid & 31;
#pragma unroll
  for (int i = 0; i < 4; i++) {
    int row = (tid >> 5) + i * 8;
    if (r0 + row < R && c0 + col < Cc) t[row][col] = s[(size_t)(r0 + row) * Cc + c0 + col];
  }
  __syncthreads();
#pragma unroll
  for (int i = 0; i < 4; i++) {
    int row = (tid >> 5) + i * 8;
    if (c0 + row < Cc && r0 + col < R) d[(size_t)(c0 + row) * R + r0 + col] = t[col][row];
  }
}

// ---- depthwise 3x3 stride-2 conv, dual-dtype x, arena weights, bf16 out ----
__global__ __launch_bounds__(256) void dwconv_k(const void* __restrict__ x,
                                                const u16* __restrict__ arena,
                                                u16* __restrict__ ki, u16* __restrict__ vi,
                                                const int* __restrict__ cnt) {
  int f32m = (*cnt >= 64);
  int b = blockIdx.x >> 8;
  int c = blockIdx.x & 255;
  float wkf[9], wvf[9];
#pragma unroll
  for (int t = 0; t < 9; t++) {
    wkf[t] = bf2f(arena[AOFF_WKDW + c * 9 + t]);
    wvf[t] = bf2f(arena[AOFF_WVDW + c * 9 + t]);
  }
  float kb = bf2f(arena[AOFF_BKDW + c]), vb = bf2f(arena[AOFF_BVDW + c]);
  size_t xbase = (size_t)(b * 256 + c) * HW;
  auto body = [&](auto LDX) {
    for (int j = threadIdx.x; j < KW; j += 256) {
      int oi = j / 28, oj = j % 28;
      float ka = kb, va = vb;
#pragma unroll
      for (int di = 0; di < 3; di++) {
        int ii = 2 * oi - 1 + di;
        if ((unsigned)ii >= 56u) continue;
#pragma unroll
        for (int dj = 0; dj < 3; dj++) {
          int ij = 2 * oj - 1 + dj;
          if ((unsigned)ij >= 56u) continue;
          float xv = LDX(ii * 56 + ij);
          ka += xv * wkf[di * 3 + dj];
          va += xv * wvf[di * 3 + dj];
        }
      }
      ki[(size_t)(b * 256 + c) * KW + j] = f2bf(ka);
      vi[(size_t)(b * 256 + c) * KW + j] = f2bf(va);
    }
  };
  if (f32m) {
    const float* xp = (const float*)x + xbase;
    body([&](int i) { return xp[i]; });
  } else {
    const u16* xp = (const u16*)x + xbase;
    body([&](int i) { return bf2f(xp[i]); });
  }
}

// ---- Q projection: q[b][p][o] = alpha * sum_c xt[b][p][c]*Wq[o][c] + beta[o] ----
__global__ __launch_bounds__(256) void proj_q_k(const u16* __restrict__ xt, const u16* __restrict__ Wq,
                                                const float* __restrict__ wsf, u16* __restrict__ q) {
  int lane = threadIdx.x & 63, wave = threadIdx.x >> 6;
  int l15 = lane & 15, quad = lane >> 4;
  int b = blockIdx.x / 49, pb = blockIdx.x % 49;
  int p0 = pb * 64 + wave * 16;
  const u16* arow = xt + ((size_t)(b * HW) + p0 + l15) * 256 + quad * 8;
  short8 af[8];
#pragma unroll
  for (int ks = 0; ks < 8; ks++) af[ks] = *(const short8*)(arow + ks * 32);
  float alpha = wsf[6];
  const float* beta = wsf + 16;
  for (int ot = 0; ot < 16; ot++) {
    const u16* brow = Wq + (size_t)(ot * 16 + l15) * 256 + quad * 8;
    f32x4 acc = {0.f, 0.f, 0.f, 0.f};
#pragma unroll
    for (int ks = 0; ks < 8; ks++) acc = MFMA16(af[ks], *(const short8*)(brow + ks * 32), acc);
    int o = ot * 16 + l15;
    float bet = beta[o];
    size_t base = ((size_t)(b * HW) + p0 + quad * 4) * 256 + o;
#pragma unroll
    for (int r = 0; r < 4; r++) q[base + (size_t)r * 256] = f2bf(alpha * acc[r] + bet);
  }
}

// ---- K projection ----
__global__ __launch_bounds__(256) void proj_k_k(const u16* __restrict__ kit, const u16* __restrict__ Wk,
                                                const u16* __restrict__ bk, u16* __restrict__ kout) {
  int lane = threadIdx.x & 63, wave = threadIdx.x >> 6;
  int l15 = lane & 15, quad = lane >> 4;
  int b = blockIdx.x / 13, jb = blockIdx.x % 13;
  int p0 = jb * 64 + wave * 16;
  if (p0 >= KW) return;
  const u16* arow = kit + ((size_t)(b * KW) + p0 + l15) * 256 + quad * 8;
  short8 af[8];
#pragma unroll
  for (int ks = 0; ks < 8; ks++) af[ks] = *(const short8*)(arow + ks * 32);
  for (int ot = 0; ot < 16; ot++) {
    const u16* brow = Wk + (size_t)(ot * 16 + l15) * 256 + quad * 8;
    f32x4 acc = {0.f, 0.f, 0.f, 0.f};
#pragma unroll
    for (int ks = 0; ks < 8; ks++) acc = MFMA16(af[ks], *(const short8*)(brow + ks * 32), acc);
    int o = ot * 16 + l15;
    float bias = bf2f(bk[o]);
    size_t base = ((size_t)(b * KW) + p0 + quad * 4) * 256 + o;
#pragma unroll
    for (int r = 0; r < 4; r++) kout[base + (size_t)r * 256] = f2bf(acc[r] + bias);
  }
}

// ---- V projection, transposed output vT[b][o][j] ----
__global__ __launch_bounds__(256) void proj_v_k(const u16* __restrict__ Wv, const u16* __restrict__ vit,
                                                const u16* __restrict__ bv, u16* __restrict__ vT) {
  int lane = threadIdx.x & 63, wave = threadIdx.x >> 6;
  int l15 = lane & 15, quad = lane >> 4;
  int b = blockIdx.x >> 4;
  int ob = (blockIdx.x >> 2) & 3;
  int js = blockIdx.x & 3;
  int o0 = ob * 64 + wave * 16;
  const u16* arow = Wv + (size_t)(o0 + l15) * 256 + quad * 8;
  short8 af[8];
#pragma unroll
  for (int ks = 0; ks < 8; ks++) af[ks] = *(const short8*)(arow + ks * 32);
  int jt0 = js * 13;
  int jt1 = (jt0 + 13 < 49) ? jt0 + 13 : 49;
  for (int jt = jt0; jt < jt1; jt++) {
    const u16* brow = vit + ((size_t)(b * KW) + jt * 16 + l15) * 256 + quad * 8;
    f32x4 acc = {0.f, 0.f, 0.f, 0.f};
#pragma unroll
    for (int ks = 0; ks < 8; ks++) acc = MFMA16(af[ks], *(const short8*)(brow + ks * 32), acc);
#pragma unroll
    for (int r = 0; r < 4; r++) {
      int o = o0 + quad * 4 + r;
      vT[((size_t)(b * 256) + o) * KW + jt * 16 + l15] = f2bf(acc[r] + bf2f(bv[o]));
    }
  }
}

// ---- fused attention: one wave per (b, h, 16-row q tile); Bbias dual-dtype ----
__global__ __launch_bounds__(64) void attn_k(const u16* __restrict__ q, const u16* __restrict__ k,
                                             const u16* __restrict__ vT, const void* __restrict__ Bb,
                                             u16* __restrict__ Ob, const int* __restrict__ cnt) {
  int f32m = (*cnt >= 64);
  int lane = threadIdx.x;
  int l15 = lane & 15, quad = lane >> 4;
  int pt = blockIdx.x % 196;
  int t = blockIdx.x / 196;
  int h = t & 7, b = t >> 3;
  int p0 = pt * 16;
  __shared__ __align__(16) u16 Pch[16][40];  // P chunk [p][32 j], row stride 80B

  const u16* qp = q + ((size_t)(b * HW) + p0 + l15) * 256 + h * 32 + quad * 8;
  short8 af = *(const short8*)qp;
  const u16* kb = k + (size_t)b * KW * 256 + h * 32 + quad * 8;
  size_t boff = ((size_t)(h * HW) + p0) * KW;

  // scores, bf16-packed: sp[jt][0] = rows(quad*4+0,+1), sp[jt][1] = rows(+2,+3); col = jt*16+l15
  u32 sp[49][2];
  auto score_loop = [&](auto LDB) {
#pragma unroll
    for (int jt = 0; jt < 49; jt++) {
      short8 bfr = *(const short8*)(kb + (size_t)(jt * 16 + l15) * 256);
      f32x4 acc = {0.f, 0.f, 0.f, 0.f};
      acc = MFMA16(af, bfr, acc);
      int col = jt * 16 + l15;
      float v0 = acc[0] + LDB(0, col);
      float v1 = acc[1] + LDB(1, col);
      float v2 = acc[2] + LDB(2, col);
      float v3 = acc[3] + LDB(3, col);
      sp[jt][0] = packbf(v0, v1);
      sp[jt][1] = packbf(v2, v3);
    }
  };
  if (f32m) {
    const float* bbf = (const float*)Bb + boff;
    score_loop([&](int r, int c) { return bbf[(size_t)(quad * 4 + r) * KW + c]; });
  } else {
    const u16* bbb = (const u16*)Bb + boff;
    score_loop([&](int r, int c) { return bf2f(bbb[(size_t)(quad * 4 + r) * KW + c]); });
  }

  float m[4] = {-1e30f, -1e30f, -1e30f, -1e30f};
#pragma unroll
  for (int jt = 0; jt < 49; jt++) {
    m[0] = fmaxf(m[0], bflo(sp[jt][0])); m[1] = fmaxf(m[1], bfhi(sp[jt][0]));
    m[2] = fmaxf(m[2], bflo(sp[jt][1])); m[3] = fmaxf(m[3], bfhi(sp[jt][1]));
  }
#pragma unroll
  for (int off = 1; off < 16; off <<= 1)
#pragma unroll
    for (int r = 0; r < 4; r++) m[r] = fmaxf(m[r], __shfl_xor(m[r], off));
  float l[4] = {0.f, 0.f, 0.f, 0.f};
#pragma unroll
  for (int jt = 0; jt < 49; jt++) {
    float e0 = __expf(bflo(sp[jt][0]) - m[0]);
    float e1 = __expf(bfhi(sp[jt][0]) - m[1]);
    float e2 = __expf(bflo(sp[jt][1]) - m[2]);
    float e3 = __expf(bfhi(sp[jt][1]) - m[3]);
    l[0] += e0; l[1] += e1; l[2] += e2; l[3] += e3;
    sp[jt][0] = packbf(e0, e1);
    sp[jt][1] = packbf(e2, e3);
  }
#pragma unroll
  for (int off = 1; off < 16; off <<= 1)
#pragma unroll
    for (int r = 0; r < 4; r++) l[r] += __shfl_xor(l[r], off);
  float inv[4];
#pragma unroll
  for (int r = 0; r < 4; r++) inv[r] = 1.f / l[r];

  // PV: 25 chunks of 32 j; P goes D-layout -> LDS -> A-layout
  f32x4 oa = {0.f, 0.f, 0.f, 0.f}, obb = {0.f, 0.f, 0.f, 0.f};
  const u16* vb = vT + ((size_t)(b * 256) + h * 32) * KW;
#pragma unroll
  for (int ch = 0; ch < 25; ch++) {
#pragma unroll
    for (int half = 0; half < 2; half++) {
      int jt = ch * 2 + half;
      u32 p0k = 0, p1k = 0;
      if (jt < 49) { p0k = sp[jt][0]; p1k = sp[jt][1]; }
      int col = half * 16 + l15;
      Pch[quad * 4 + 0][col] = (u16)(p0k & 0xFFFFu);
      Pch[quad * 4 + 1][col] = (u16)(p0k >> 16);
      Pch[quad * 4 + 2][col] = (u16)(p1k & 0xFFFFu);
      Pch[quad * 4 + 3][col] = (u16)(p1k >> 16);
    }
    __syncthreads();
    short8 pf = *(const short8*)(&Pch[l15][quad * 8]);
    int jo = ch * 32 + quad * 8;
    if (jo > 776) jo = 776;  // clamp; those B values only meet P==0 (j>=784 pad)
    short8 v0 = *(const short8*)(vb + (size_t)l15 * KW + jo);
    short8 v1 = *(const short8*)(vb + (size_t)(16 + l15) * KW + jo);
    oa  = MFMA16(pf, v0, oa);
    obb = MFMA16(pf, v1, obb);
    __syncthreads();
  }
  size_t obase = ((size_t)(b * HW) + p0 + quad * 4) * 256 + h * 32 + l15;
#pragma unroll
  for (int r = 0; r < 4; r++) {
    Ob[obase + (size_t)r * 256]      = f2bf(oa[r] * inv[r]);
    Ob[obase + (size_t)r * 256 + 16] = f2bf(obb[r] * inv[r]);
  }
}

// ---- O projection + .view-quirk residual; dual-dtype x read and out write ----
__global__ __launch_bounds__(256) void proj_o_k(const u16* __restrict__ Ob, const u16* __restrict__ Wo,
                                                const u16* __restrict__ bo, const void* __restrict__ x,
                                                void* __restrict__ out, const int* __restrict__ cnt) {
  int f32m = (*cnt >= 64);
  int lane = threadIdx.x & 63, wave = threadIdx.x >> 6;
  int l15 = lane & 15, quad = lane >> 4;
  int b = blockIdx.x / 49, pb = blockIdx.x % 49;
  int p0 = pb * 64 + wave * 16;
  const u16* arow = Ob + ((size_t)(b * HW) + p0 + l15) * 256 + quad * 8;
  short8 af[8];
#pragma unroll
  for (int ks = 0; ks < 8; ks++) af[ks] = *(const short8*)(arow + ks * 32);
  for (int ot = 0; ot < 16; ot++) {
    const u16* brow = Wo + (size_t)(ot * 16 + l15) * 256 + quad * 8;
    f32x4 acc = {0.f, 0.f, 0.f, 0.f};
#pragma unroll
    for (int ks = 0; ks < 8; ks++) acc = MFMA16(af[ks], *(const short8*)(brow + ks * 32), acc);
    int o = ot * 16 + l15;
    float bias = bf2f(bo[o]);
    if (f32m) {
      const float* xf = (const float*)x;
      float* of = (float*)out;
#pragma unroll
      for (int r = 0; r < 4; r++) {
        size_t idx = ((size_t)(b * HW) + p0 + quad * 4 + r) * 256 + o;
        of[idx] = acc[r] + bias + xf[idx];
      }
    } else {
      const u16* xb = (const u16*)x;
      u16* ob_ = (u16*)out;
#pragma unroll
      for (int r = 0; r < 4; r++) {
        size_t idx = ((size_t)(b * HW) + p0 + quad * 4 + r) * 256 + o;
        ob_[idx] = f2bf(acc[r] + bias + bf2f(xb[idx]));
      }
    }
  }
}

extern "C" void kernel_launch(void* const* d_in, const int* in_sizes, int n_in,
                              void* d_out, int out_size, void* d_ws, size_t ws_size,
                              hipStream_t stream) {
  (void)in_sizes; (void)n_in; (void)out_size; (void)ws_size;
  const void* x = d_in[0];
  char* ws = (char*)d_ws;
  int* cnt = (int*)(ws + OFF_CNT);
  u16* arena = (u16*)(ws + OFF_W);
  u16* xt  = (u16*)(ws + OFF_XT);
  u16* kit = (u16*)(ws + OFF_KIT);
  u16* vit = (u16*)(ws + OFF_VIT);
  u16* ki  = (u16*)(ws + OFF_KI);   // then k-proj output
  u16* vi  = (u16*)(ws + OFF_VI);   // then vT
  u16* qb  = (u16*)(ws + OFF_Q);
  u16* Obuf = (u16*)(ws + OFF_O);   // overlays xt

  CvtArgs a;
  const int srcidx[12] = {5, 7, 9, 11, 1, 3, 2, 4, 6, 8, 10, 12};
  const int dofs[12] = {AOFF_WQ, AOFF_WK, AOFF_WV, AOFF_WO, AOFF_WKDW, AOFF_WVDW,
                        AOFF_BKDW, AOFF_BVDW, AOFF_BQ, AOFF_BK, AOFF_BV, AOFF_BO};
  const int ns[12] = {65536, 65536, 65536, 65536, 2304, 2304, 256, 256, 256, 256, 256, 256};
  for (int i = 0; i < 12; i++) { a.src[i] = d_in[srcidx[i]]; a.dstoff[i] = dofs[i]; a.n[i] = ns[i]; }

  hipMemsetAsync(d_ws, 0, 8192, stream);  // zero acc + detect counter
  detect_k<<<1, 256, 0, stream>>>((const u32*)x, cnt);
  cvtw_k<<<dim3(32, 12), 256, 0, stream>>>(a, arena, cnt);
  reduce_k<<<1024, 256, 0, stream>>>(x, (double*)d_ws, cnt);
  prep_k<<<1, 256, 0, stream>>>(arena + AOFF_WQ, arena + AOFF_BQ, (float*)d_ws);
  transpose_x_k<<<dim3(98, 8, 8), 256, 0, stream>>>(x, xt, cnt);
  dwconv_k<<<2048, 256, 0, stream>>>(x, arena, ki, vi, cnt);
  transpose_k<<<dim3(25, 8, 8), 256, 0, stream>>>(ki, kit, 256, KW);
  transpose_k<<<dim3(25, 8, 8), 256, 0, stream>>>(vi, vit, 256, KW);
  proj_k_k<<<104, 256, 0, stream>>>(kit, arena + AOFF_WK, arena + AOFF_BK, ki);
  proj_v_k<<<128, 256, 0, stream>>>(arena + AOFF_WV, vit, arena + AOFF_BV, vi);
  proj_q_k<<<392, 256, 0, stream>>>(xt, arena + AOFF_WQ, (const float*)d_ws, qb);
  attn_k<<<12544, 64, 0, stream>>>(qb, ki, vi, d_in[13], Obuf, cnt);
  proj_o_k<<<392, 256, 0, stream>>>(Obuf, arena + AOFF_WO, arena + AOFF_BO, x, d_out, cnt);
}